// Round 7
// baseline (382.780 us; speedup 1.0000x reference)
//
#include <hip/hip_runtime.h>

#define NPOSTS 2048
#define SEQ 64
#define W2V 300
#define NH 5
#define HD 60
#define S2VD 256
#define HIDD 256
#define NEDGE 2047
#define UDIM 1500

#define GLOAD_LDS(g, l) \
    __builtin_amdgcn_global_load_lds((const __attribute__((address_space(1))) void*)(g), \
                                     (__attribute__((address_space(3))) void*)(l), 16, 0, 0)

// ================= Stage 0a: WsWo = Ws@Wo [256x300]; bias3A = bs + Ws@bo =================
__global__ __launch_bounds__(320) void k_wfoldA(
    const float* __restrict__ Ws, const float* __restrict__ Wo,
    const float* __restrict__ bo, const float* __restrict__ bs,
    float* __restrict__ WsWo, float* __restrict__ bias3A)
{
    const int r0 = blockIdx.x * 16;
    const int tid = threadIdx.x;
    __shared__ float sT[W2V][16];   // sT[k][r] = Ws[r0+r][k]
    for (int i = tid; i < 16 * W2V; i += 320) {
        int r = i / W2V, k = i % W2V;
        sT[k][r] = Ws[(size_t)(r0 + r) * W2V + k];
    }
    __syncthreads();
    if (tid <= W2V) {
        float a[16];
        #pragma unroll
        for (int r = 0; r < 16; ++r) a[r] = 0.f;
        for (int k = 0; k < W2V; ++k) {
            float wv = (tid < W2V) ? Wo[(size_t)k * W2V + tid] : bo[k];
            const float4* s4 = reinterpret_cast<const float4*>(&sT[k][0]);
            float4 q0 = s4[0], q1 = s4[1], q2 = s4[2], q3 = s4[3];
            float qq[16] = {q0.x,q0.y,q0.z,q0.w, q1.x,q1.y,q1.z,q1.w,
                            q2.x,q2.y,q2.z,q2.w, q3.x,q3.y,q3.z,q3.w};
            #pragma unroll
            for (int r = 0; r < 16; ++r) a[r] = fmaf(wv, qq[r], a[r]);
        }
        if (tid < W2V) {
            #pragma unroll
            for (int r = 0; r < 16; ++r) WsWo[(size_t)(r0 + r) * W2V + tid] = a[r];
        } else {
            #pragma unroll
            for (int r = 0; r < 16; ++r) bias3A[r0 + r] = bs[r0 + r] + a[r];
        }
    }
}

// ===== Stage 0b: WfoldT[h*300+c][t] = sum_d WsWo[t][h*60+d]*Wv[600+h*60+d][c]; bpart = WsWo_h@bv_h =====
__global__ __launch_bounds__(320) void k_wfold2(
    const float* __restrict__ WsWo, const float* __restrict__ Wqkv, const float* __restrict__ bqkv,
    float* __restrict__ WfoldT, float* __restrict__ bpart)
{
    const int r0 = blockIdx.x * 16;
    const int h = blockIdx.y;
    const int tid = threadIdx.x;
    __shared__ float sT[HD][16];    // sT[d][r] = WsWo[r0+r][h*60+d]
    for (int i = tid; i < 16 * HD; i += 320) {
        int r = i / HD, d = i % HD;
        sT[d][r] = WsWo[(size_t)(r0 + r) * W2V + h * HD + d];
    }
    __syncthreads();
    if (tid <= W2V) {
        float a[16];
        #pragma unroll
        for (int r = 0; r < 16; ++r) a[r] = 0.f;
        for (int d = 0; d < HD; ++d) {
            float wv = (tid < W2V) ? Wqkv[(size_t)(2 * W2V + h * HD + d) * W2V + tid]
                                   : bqkv[2 * W2V + h * HD + d];
            const float4* s4 = reinterpret_cast<const float4*>(&sT[d][0]);
            float4 q0 = s4[0], q1 = s4[1], q2 = s4[2], q3 = s4[3];
            float qq[16] = {q0.x,q0.y,q0.z,q0.w, q1.x,q1.y,q1.z,q1.w,
                            q2.x,q2.y,q2.z,q2.w, q3.x,q3.y,q3.z,q3.w};
            #pragma unroll
            for (int r = 0; r < 16; ++r) a[r] = fmaf(wv, qq[r], a[r]);
        }
        if (tid < W2V) {
            // transposed store: WfoldT[k][t], k = h*300 + tid, t = r0+r
            #pragma unroll
            for (int r = 0; r < 16; ++r)
                WfoldT[(size_t)(h * W2V + tid) * S2VD + (r0 + r)] = a[r];
        } else {
            #pragma unroll
            for (int r = 0; r < 16; ++r) bpart[h * S2VD + r0 + r] = a[r];
        }
    }
}

// ================= Stage 0c: WqT[c][r] = Wq[r][c]  (300x300) =================
__global__ __launch_bounds__(256) void k_wqT(
    const float* __restrict__ W, float* __restrict__ WT)
{
    int i = blockIdx.x * 256 + threadIdx.x;
    if (i < W2V * W2V) {
        int r = i / W2V, c = i - r * W2V;
        WT[(size_t)c * W2V + r] = W[i];
    }
}

// ===== Stage 1a: Q = Emb0 @ Wq^T + bq; 8 posts/block, 3-way K-split, scalar-broadcast e =====
__global__ __launch_bounds__(900) void k_q(
    const int* __restrict__ nodeText, const float* __restrict__ embed_w,
    const float* __restrict__ WqT, const float* __restrict__ bqkv,
    float* __restrict__ Qout)
{
    __shared__ float part[2][W2V * 9];   // stride 9 -> conflict-free
    const int p0 = blockIdx.x * 8;
    const int tid = threadIdx.x;
    const int t = tid % W2V;      // output dim 0..299
    const int kg = tid / W2V;     // K-group 0..2 (K=100 each)

    // 8 wave-uniform token ids -> scalar loads
    const int tok0 = nodeText[(size_t)(p0 + 0) * SEQ];
    const int tok1 = nodeText[(size_t)(p0 + 1) * SEQ];
    const int tok2 = nodeText[(size_t)(p0 + 2) * SEQ];
    const int tok3 = nodeText[(size_t)(p0 + 3) * SEQ];
    const int tok4 = nodeText[(size_t)(p0 + 4) * SEQ];
    const int tok5 = nodeText[(size_t)(p0 + 5) * SEQ];
    const int tok6 = nodeText[(size_t)(p0 + 6) * SEQ];
    const int tok7 = nodeText[(size_t)(p0 + 7) * SEQ];
    const float* er0 = embed_w + (size_t)tok0 * W2V + kg * 100;
    const float* er1 = embed_w + (size_t)tok1 * W2V + kg * 100;
    const float* er2 = embed_w + (size_t)tok2 * W2V + kg * 100;
    const float* er3 = embed_w + (size_t)tok3 * W2V + kg * 100;
    const float* er4 = embed_w + (size_t)tok4 * W2V + kg * 100;
    const float* er5 = embed_w + (size_t)tok5 * W2V + kg * 100;
    const float* er6 = embed_w + (size_t)tok6 * W2V + kg * 100;
    const float* er7 = embed_w + (size_t)tok7 * W2V + kg * 100;

    float a0 = 0.f, a1 = 0.f, a2 = 0.f, a3 = 0.f, a4 = 0.f, a5 = 0.f, a6 = 0.f, a7 = 0.f;
    const float* wp = WqT + (size_t)(kg * 100) * W2V + t;
    for (int k4 = 0; k4 < 25; ++k4) {
        const float w0 = wp[(size_t)(4 * k4 + 0) * W2V];
        const float w1 = wp[(size_t)(4 * k4 + 1) * W2V];
        const float w2 = wp[(size_t)(4 * k4 + 2) * W2V];
        const float w3 = wp[(size_t)(4 * k4 + 3) * W2V];
        const float4 e0 = *reinterpret_cast<const float4*>(er0 + 4 * k4);
        const float4 e1 = *reinterpret_cast<const float4*>(er1 + 4 * k4);
        const float4 e2 = *reinterpret_cast<const float4*>(er2 + 4 * k4);
        const float4 e3 = *reinterpret_cast<const float4*>(er3 + 4 * k4);
        const float4 e4 = *reinterpret_cast<const float4*>(er4 + 4 * k4);
        const float4 e5 = *reinterpret_cast<const float4*>(er5 + 4 * k4);
        const float4 e6 = *reinterpret_cast<const float4*>(er6 + 4 * k4);
        const float4 e7 = *reinterpret_cast<const float4*>(er7 + 4 * k4);
        a0 = fmaf(w0, e0.x, a0); a0 = fmaf(w1, e0.y, a0); a0 = fmaf(w2, e0.z, a0); a0 = fmaf(w3, e0.w, a0);
        a1 = fmaf(w0, e1.x, a1); a1 = fmaf(w1, e1.y, a1); a1 = fmaf(w2, e1.z, a1); a1 = fmaf(w3, e1.w, a1);
        a2 = fmaf(w0, e2.x, a2); a2 = fmaf(w1, e2.y, a2); a2 = fmaf(w2, e2.z, a2); a2 = fmaf(w3, e2.w, a2);
        a3 = fmaf(w0, e3.x, a3); a3 = fmaf(w1, e3.y, a3); a3 = fmaf(w2, e3.z, a3); a3 = fmaf(w3, e3.w, a3);
        a4 = fmaf(w0, e4.x, a4); a4 = fmaf(w1, e4.y, a4); a4 = fmaf(w2, e4.z, a4); a4 = fmaf(w3, e4.w, a4);
        a5 = fmaf(w0, e5.x, a5); a5 = fmaf(w1, e5.y, a5); a5 = fmaf(w2, e5.z, a5); a5 = fmaf(w3, e5.w, a5);
        a6 = fmaf(w0, e6.x, a6); a6 = fmaf(w1, e6.y, a6); a6 = fmaf(w2, e6.z, a6); a6 = fmaf(w3, e6.w, a6);
        a7 = fmaf(w0, e7.x, a7); a7 = fmaf(w1, e7.y, a7); a7 = fmaf(w2, e7.z, a7); a7 = fmaf(w3, e7.w, a7);
    }

    if (kg != 0) {
        float* pp = &part[kg - 1][t * 9];
        pp[0] = a0; pp[1] = a1; pp[2] = a2; pp[3] = a3;
        pp[4] = a4; pp[5] = a5; pp[6] = a6; pp[7] = a7;
    }
    __syncthreads();
    if (kg == 0) {
        const float* q0p = &part[0][t * 9];
        const float* q1p = &part[1][t * 9];
        const float b = bqkv[t];
        float r0v = a0 + q0p[0] + q1p[0] + b;
        float r1v = a1 + q0p[1] + q1p[1] + b;
        float r2v = a2 + q0p[2] + q1p[2] + b;
        float r3v = a3 + q0p[3] + q1p[3] + b;
        float r4v = a4 + q0p[4] + q1p[4] + b;
        float r5v = a5 + q0p[5] + q1p[5] + b;
        float r6v = a6 + q0p[6] + q1p[6] + b;
        float r7v = a7 + q0p[7] + q1p[7] + b;
        Qout[(size_t)(p0 + 0) * W2V + t] = r0v;
        Qout[(size_t)(p0 + 1) * W2V + t] = r1v;
        Qout[(size_t)(p0 + 2) * W2V + t] = r2v;
        Qout[(size_t)(p0 + 3) * W2V + t] = r3v;
        Qout[(size_t)(p0 + 4) * W2V + t] = r4v;
        Qout[(size_t)(p0 + 5) * W2V + t] = r5v;
        Qout[(size_t)(p0 + 6) * W2V + t] = r6v;
        Qout[(size_t)(p0 + 7) * W2V + t] = r7v;
    }
}

// ================= Stage 1b: u[p][h*300+c] = sum_d Q[p][h*60+d] * Wk[300+h*60+d][c] =================
__global__ __launch_bounds__(320) void k_u(
    const float* __restrict__ Q, const float* __restrict__ Wqkv, float* __restrict__ uout)
{
    const int r0 = blockIdx.x * 16;
    const int h = blockIdx.y;
    const int tid = threadIdx.x;
    __shared__ float sT[HD][16];   // sT[d][r] = Q[r0+r][h*60+d]
    for (int i = tid; i < 16 * HD; i += 320) {
        int r = i / HD, d = i % HD;
        sT[d][r] = Q[(size_t)(r0 + r) * W2V + h * HD + d];
    }
    __syncthreads();
    if (tid < W2V) {
        float a[16];
        #pragma unroll
        for (int r = 0; r < 16; ++r) a[r] = 0.f;
        for (int d = 0; d < HD; ++d) {
            float wv = Wqkv[(size_t)(W2V + h * HD + d) * W2V + tid];   // coalesced
            const float4* s4 = reinterpret_cast<const float4*>(&sT[d][0]);
            float4 q0 = s4[0], q1 = s4[1], q2 = s4[2], q3 = s4[3];
            float qq[16] = {q0.x,q0.y,q0.z,q0.w, q1.x,q1.y,q1.z,q1.w,
                            q2.x,q2.y,q2.z,q2.w, q3.x,q3.y,q3.z,q3.w};
            #pragma unroll
            for (int r = 0; r < 16; ++r) a[r] = fmaf(wv, qq[r], a[r]);
        }
        #pragma unroll
        for (int r = 0; r < 16; ++r)
            uout[(size_t)(r0 + r) * UDIM + h * W2V + tid] = a[r];
    }
}

// ===== Stage 1c: scores + softmax + e; 2 posts/block, async global_load_lds Emb staging =====
__global__ __launch_bounds__(512) void k_att(
    const int* __restrict__ nodeText, const float* __restrict__ embed_w,
    float* __restrict__ ue)
{
    __shared__ float sE[2 * SEQ * W2V];    // 153600 B flat (DMA dest must be linear)
    __shared__ float satt[2][NH][SEQ];     // 2560 B
    __shared__ int   stoks[2][SEQ];        // 512 B

    const int p0 = blockIdx.x * 2;
    const int tid = threadIdx.x;
    const int wave = tid >> 6, lane = tid & 63;

    if (tid < 2 * SEQ) stoks[tid >> 6][tid & 63] = nodeText[(size_t)p0 * SEQ + tid];
    __syncthreads();

    // async DMA: 9600 float4-chunks; chunk i -> sE[4i..4i+3]
    #pragma unroll 3
    for (int it = 0; it < 18; ++it) {
        int i = it * 512 + tid;
        int pp = i / 4800, idx = i % 4800;
        int row = idx / 75, c4 = idx - row * 75;
        const float* src = embed_w + (size_t)stoks[pp][row] * W2V + c4 * 4;
        GLOAD_LDS(src, &sE[i * 4]);
    }
    if (wave < 6) {   // tail: 384 chunks, wave-uniform predicate
        int i = 18 * 512 + tid;
        int pp = i / 4800, idx = i % 4800;
        int row = idx / 75, c4 = idx - row * 75;
        const float* src = embed_w + (size_t)stoks[pp][row] * W2V + c4 * 4;
        GLOAD_LDS(src, &sE[i * 4]);
    }
    asm volatile("s_waitcnt vmcnt(0)" ::: "memory");
    __syncthreads();

    // scores: 10 (post,head) tasks on 8 waves; lane j = token j; u wave-uniform
    const float SC = 0.12909944487358056f;  // 60^-0.5
    for (int task = wave; task < 2 * NH; task += 8) {
        int pp = task / NH, h = task - pp * NH;
        const float4* u4 = reinterpret_cast<const float4*>(ue + (size_t)(p0 + pp) * UDIM + h * W2V);
        const float* er = &sE[(pp * SEQ + lane) * W2V];
        float acc = 0.f;
        #pragma unroll 5
        for (int c4 = 0; c4 < 75; ++c4) {
            float4 uv = u4[c4];
            float4 ev = *reinterpret_cast<const float4*>(er + c4 * 4);
            acc = fmaf(uv.x, ev.x, acc);
            acc = fmaf(uv.y, ev.y, acc);
            acc = fmaf(uv.z, ev.z, acc);
            acc = fmaf(uv.w, ev.w, acc);
        }
        float ex = expf(acc * SC);
        float l = ex;
        #pragma unroll
        for (int off = 32; off > 0; off >>= 1) l += __shfl_xor(l, off);
        satt[pp][h][lane] = ex / l;
    }
    __syncthreads();

    // e[pp][h][c] = sum_j att[pp][h][j] * Emb[pp][j][c]
    for (int t = tid; t < 2 * NH * 75; t += 512) {
        int pp = t / 375, r = t - pp * 375;
        int h = r / 75, c4 = r - h * 75;
        const float* att = &satt[pp][h][0];
        const float* eb = &sE[pp * SEQ * W2V + c4 * 4];
        float4 a = make_float4(0.f, 0.f, 0.f, 0.f);
        #pragma unroll 4
        for (int j = 0; j < SEQ; ++j) {
            float av = att[j];
            float4 ev = *reinterpret_cast<const float4*>(eb + j * W2V);
            a.x = fmaf(av, ev.x, a.x);
            a.y = fmaf(av, ev.y, a.y);
            a.z = fmaf(av, ev.z, a.z);
            a.w = fmaf(av, ev.w, a.w);
        }
        *reinterpret_cast<float4*>(ue + (size_t)(p0 + pp) * UDIM + h * W2V + c4 * 4) = a;
    }
}

// ===== Stage 1d: s2v = tanh(WfoldT^T @ e + bias3); 8 posts/block, 3-way K-split (K=500) =====
__global__ __launch_bounds__(768) void k_s2v(
    const float* __restrict__ e, const float* __restrict__ WfoldT,
    const float* __restrict__ bias3A, const float* __restrict__ bpart,
    float* __restrict__ s2v_out)
{
    __shared__ float part[2][S2VD * 9];   // stride 9 -> conflict-free
    const int p0 = blockIdx.x * 8;
    const int tid = threadIdx.x;
    const int t = tid & 255;      // output dim
    const int kg = tid >> 8;      // K-group 0..2 (K=500 each)

    const float* er0 = e + (size_t)(p0 + 0) * UDIM + kg * 500;
    const float* er1 = e + (size_t)(p0 + 1) * UDIM + kg * 500;
    const float* er2 = e + (size_t)(p0 + 2) * UDIM + kg * 500;
    const float* er3 = e + (size_t)(p0 + 3) * UDIM + kg * 500;
    const float* er4 = e + (size_t)(p0 + 4) * UDIM + kg * 500;
    const float* er5 = e + (size_t)(p0 + 5) * UDIM + kg * 500;
    const float* er6 = e + (size_t)(p0 + 6) * UDIM + kg * 500;
    const float* er7 = e + (size_t)(p0 + 7) * UDIM + kg * 500;

    float a0 = 0.f, a1 = 0.f, a2 = 0.f, a3 = 0.f, a4 = 0.f, a5 = 0.f, a6 = 0.f, a7 = 0.f;
    const float* wp = WfoldT + (size_t)(kg * 500) * S2VD + t;
    for (int k4 = 0; k4 < 125; ++k4) {
        const float w0 = wp[(size_t)(4 * k4 + 0) * S2VD];
        const float w1 = wp[(size_t)(4 * k4 + 1) * S2VD];
        const float w2 = wp[(size_t)(4 * k4 + 2) * S2VD];
        const float w3 = wp[(size_t)(4 * k4 + 3) * S2VD];
        const float4 e0 = *reinterpret_cast<const float4*>(er0 + 4 * k4);
        const float4 e1 = *reinterpret_cast<const float4*>(er1 + 4 * k4);
        const float4 e2 = *reinterpret_cast<const float4*>(er2 + 4 * k4);
        const float4 e3 = *reinterpret_cast<const float4*>(er3 + 4 * k4);
        const float4 e4 = *reinterpret_cast<const float4*>(er4 + 4 * k4);
        const float4 e5 = *reinterpret_cast<const float4*>(er5 + 4 * k4);
        const float4 e6 = *reinterpret_cast<const float4*>(er6 + 4 * k4);
        const float4 e7 = *reinterpret_cast<const float4*>(er7 + 4 * k4);
        a0 = fmaf(w0, e0.x, a0); a0 = fmaf(w1, e0.y, a0); a0 = fmaf(w2, e0.z, a0); a0 = fmaf(w3, e0.w, a0);
        a1 = fmaf(w0, e1.x, a1); a1 = fmaf(w1, e1.y, a1); a1 = fmaf(w2, e1.z, a1); a1 = fmaf(w3, e1.w, a1);
        a2 = fmaf(w0, e2.x, a2); a2 = fmaf(w1, e2.y, a2); a2 = fmaf(w2, e2.z, a2); a2 = fmaf(w3, e2.w, a2);
        a3 = fmaf(w0, e3.x, a3); a3 = fmaf(w1, e3.y, a3); a3 = fmaf(w2, e3.z, a3); a3 = fmaf(w3, e3.w, a3);
        a4 = fmaf(w0, e4.x, a4); a4 = fmaf(w1, e4.y, a4); a4 = fmaf(w2, e4.z, a4); a4 = fmaf(w3, e4.w, a4);
        a5 = fmaf(w0, e5.x, a5); a5 = fmaf(w1, e5.y, a5); a5 = fmaf(w2, e5.z, a5); a5 = fmaf(w3, e5.w, a5);
        a6 = fmaf(w0, e6.x, a6); a6 = fmaf(w1, e6.y, a6); a6 = fmaf(w2, e6.z, a6); a6 = fmaf(w3, e6.w, a6);
        a7 = fmaf(w0, e7.x, a7); a7 = fmaf(w1, e7.y, a7); a7 = fmaf(w2, e7.z, a7); a7 = fmaf(w3, e7.w, a7);
    }

    if (kg != 0) {
        float* pp = &part[kg - 1][t * 9];
        pp[0] = a0; pp[1] = a1; pp[2] = a2; pp[3] = a3;
        pp[4] = a4; pp[5] = a5; pp[6] = a6; pp[7] = a7;
    }
    __syncthreads();
    if (kg == 0) {
        const float* q0p = &part[0][t * 9];
        const float* q1p = &part[1][t * 9];
        const float bias = bias3A[t] + bpart[t] + bpart[256 + t] + bpart[512 + t]
                         + bpart[768 + t] + bpart[1024 + t];
        s2v_out[(size_t)(p0 + 0) * S2VD + t] = tanhf(a0 + q0p[0] + q1p[0] + bias);
        s2v_out[(size_t)(p0 + 1) * S2VD + t] = tanhf(a1 + q0p[1] + q1p[1] + bias);
        s2v_out[(size_t)(p0 + 2) * S2VD + t] = tanhf(a2 + q0p[2] + q1p[2] + bias);
        s2v_out[(size_t)(p0 + 3) * S2VD + t] = tanhf(a3 + q0p[3] + q1p[3] + bias);
        s2v_out[(size_t)(p0 + 4) * S2VD + t] = tanhf(a4 + q0p[4] + q1p[4] + bias);
        s2v_out[(size_t)(p0 + 5) * S2VD + t] = tanhf(a5 + q0p[5] + q1p[5] + bias);
        s2v_out[(size_t)(p0 + 6) * S2VD + t] = tanhf(a6 + q0p[6] + q1p[6] + bias);
        s2v_out[(size_t)(p0 + 7) * S2VD + t] = tanhf(a7 + q0p[7] + q1p[7] + bias);
    }
}

// ================= Stage 2: GCN branches (blockIdx.y = branch: 0=TD, 1=BU) =================

__global__ __launch_bounds__(256) void k_deg(
    const int* __restrict__ eiTD, const int* __restrict__ eiBU, int* __restrict__ deg)
{
    const int b = blockIdx.y;
    const int* ei = b ? eiBU : eiTD;
    int e = blockIdx.x * 256 + threadIdx.x;
    if (e < NEDGE) atomicAdd(&deg[b * NPOSTS + ei[NEDGE + e]], 1);
}

__global__ __launch_bounds__(256) void k_gemm1(
    const float* __restrict__ x, const float* __restrict__ wtd, const float* __restrict__ wbu,
    const float* __restrict__ btd, const float* __restrict__ bbu, const int* __restrict__ deg,
    float* __restrict__ hout, float* __restrict__ cout_)
{
    const int b = blockIdx.y;
    const float* w = b ? wbu : wtd;
    const float* bias = b ? bbu : btd;
    float* hb = hout + (size_t)b * NPOSTS * HIDD;
    float* cb = cout_ + (size_t)b * NPOSTS * HIDD;
    const int* dg = deg + b * NPOSTS;
    const int r0 = blockIdx.x * 16;
    const int tid = threadIdx.x;
    __shared__ float sx[16][S2VD];
    for (int i = tid; i < 16 * S2VD; i += 256)
        sx[i / S2VD][i % S2VD] = x[(size_t)(r0 + i / S2VD) * S2VD + (i % S2VD)];
    __syncthreads();
    float acc[16];
    #pragma unroll
    for (int r = 0; r < 16; ++r) acc[r] = 0.f;
    const float4* wr4 = reinterpret_cast<const float4*>(w + (size_t)tid * S2VD);
    for (int c4 = 0; c4 < 64; ++c4) {
        float4 w4 = wr4[c4];
        #pragma unroll
        for (int r = 0; r < 16; ++r) {
            const float4 v = *reinterpret_cast<const float4*>(&sx[r][c4 * 4]);
            acc[r] = fmaf(w4.x, v.x, acc[r]);
            acc[r] = fmaf(w4.y, v.y, acc[r]);
            acc[r] = fmaf(w4.z, v.z, acc[r]);
            acc[r] = fmaf(w4.w, v.w, acc[r]);
        }
    }
    float bv = bias[tid];
    #pragma unroll
    for (int r = 0; r < 16; ++r) {
        int n = r0 + r;
        float dinv = 1.f / (float)(dg[n] + 1);
        hb[(size_t)n * HIDD + tid] = acc[r];
        cb[(size_t)n * HIDD + tid] = bv + acc[r] * dinv;
    }
}

__global__ __launch_bounds__(256) void k_gemm2(
    const float* __restrict__ c1, const float* __restrict__ w2td, const float* __restrict__ w2bu,
    const float* __restrict__ btd, const float* __restrict__ bbu, const int* __restrict__ deg,
    const float* __restrict__ rootv, float* __restrict__ hout, float* __restrict__ cout_)
{
    const int b = blockIdx.y;
    const float* w = b ? w2bu : w2td;
    const float* bias = b ? bbu : btd;
    const float* xin = c1 + (size_t)b * NPOSTS * HIDD;
    float* hb = hout + (size_t)b * NPOSTS * HIDD;
    float* cb = cout_ + (size_t)b * NPOSTS * HIDD;
    const int* dg = deg + b * NPOSTS;
    const int r0 = blockIdx.x * 16;
    const int tid = threadIdx.x;
    __shared__ float sx[16][HIDD];
    for (int i = tid; i < 16 * HIDD; i += 256)
        sx[i / HIDD][i % HIDD] = fmaxf(xin[(size_t)(r0 + i / HIDD) * HIDD + (i % HIDD)], 0.f);
    __syncthreads();
    float acc[16];
    const float rv = rootv[b * HIDD + tid];
    #pragma unroll
    for (int r = 0; r < 16; ++r) acc[r] = rv;
    const float4* wr4 = reinterpret_cast<const float4*>(w + (size_t)tid * 512);
    for (int c4 = 0; c4 < 64; ++c4) {
        float4 w4 = wr4[c4];
        #pragma unroll
        for (int r = 0; r < 16; ++r) {
            const float4 v = *reinterpret_cast<const float4*>(&sx[r][c4 * 4]);
            acc[r] = fmaf(w4.x, v.x, acc[r]);
            acc[r] = fmaf(w4.y, v.y, acc[r]);
            acc[r] = fmaf(w4.z, v.z, acc[r]);
            acc[r] = fmaf(w4.w, v.w, acc[r]);
        }
    }
    float bv = bias[tid];
    #pragma unroll
    for (int r = 0; r < 16; ++r) {
        int n = r0 + r;
        float dinv = 1.f / (float)(dg[n] + 1);
        hb[(size_t)n * HIDD + tid] = acc[r];
        cb[(size_t)n * HIDD + tid] = bv + acc[r] * dinv;
    }
}

__global__ __launch_bounds__(256) void k_scat(
    const int* __restrict__ eiTD, const int* __restrict__ eiBU,
    const float* __restrict__ h, const int* __restrict__ deg, float* __restrict__ cacc)
{
    const int b = blockIdx.y, e = blockIdx.x, tid = threadIdx.x;
    const int* ei = b ? eiBU : eiTD;
    const int s = ei[e], d = ei[NEDGE + e];
    const int* dg = deg + b * NPOSTS;
    float norm = rsqrtf((float)(dg[s] + 1)) * rsqrtf((float)(dg[d] + 1));
    const float* hb = h + (size_t)b * NPOSTS * HIDD;
    float* cb = cacc + (size_t)b * NPOSTS * HIDD;
    atomicAdd(&cb[(size_t)d * HIDD + tid], norm * hb[(size_t)s * HIDD + tid]);
}

__global__ __launch_bounds__(256) void k_root(
    const float* __restrict__ s2v, const float* __restrict__ c1,
    const float* __restrict__ w2td, const float* __restrict__ w2bu,
    const int* __restrict__ rootPtr, float* __restrict__ rootv, float* __restrict__ c1root)
{
    const int b = blockIdx.y, tid = threadIdx.x;
    const float* w2 = b ? w2bu : w2td;
    const int root = rootPtr[0];
    __shared__ float sx[S2VD];
    sx[tid] = fmaxf(s2v[(size_t)root * S2VD + tid], 0.f);
    __syncthreads();
    const float* cb = c1 + (size_t)b * NPOSTS * HIDD;
    c1root[b * HIDD + tid] = cb[(size_t)root * HIDD + tid];
    const float* wr = w2 + (size_t)tid * 512 + 256;
    float acc = 0.f;
    #pragma unroll 4
    for (int c = 0; c < S2VD; ++c) acc = fmaf(wr[c], sx[c], acc);
    rootv[b * HIDD + tid] = acc;
}

__global__ __launch_bounds__(256) void k_reduce(
    const float* __restrict__ cacc, float* __restrict__ msum)
{
    const int b = blockIdx.y, tid = threadIdx.x;
    const int base = blockIdx.x * 32;
    const float* cb = cacc + (size_t)b * NPOSTS * HIDD;
    float local = 0.f;
    #pragma unroll 4
    for (int r = 0; r < 32; ++r) local += fmaxf(cb[(size_t)(base + r) * HIDD + tid], 0.f);
    atomicAdd(&msum[b * HIDD + tid], local);
}

__global__ __launch_bounds__(256) void k_final(
    const float* __restrict__ c1root, const float* __restrict__ msum,
    const float* __restrict__ fc_w, const float* __restrict__ fc_b, float* __restrict__ outp)
{
    const int tid = threadIdx.x;
    __shared__ float sf[1024];
    for (int k = tid; k < 1024; k += 256) {
        int seg = k >> 8, idx = k & 255;
        float v;
        if (seg == 0)      v = c1root[idx];
        else if (seg == 1) v = msum[idx] * (1.f / (float)NPOSTS);
        else if (seg == 2) v = c1root[256 + idx];
        else               v = msum[256 + idx] * (1.f / (float)NPOSTS);
        sf[k] = v;
    }
    __syncthreads();
    const int t = tid >> 6, lane = tid & 63;
    float part = 0.f;
    for (int k = lane; k < 1024; k += 64) part = fmaf(fc_w[t * 1024 + k], sf[k], part);
    #pragma unroll
    for (int off = 32; off > 0; off >>= 1) part += __shfl_down(part, off);
    if (lane == 0) outp[t] = part + fc_b[t];
}

extern "C" void kernel_launch(void* const* d_in, const int* in_sizes, int n_in,
                              void* d_out, int out_size, void* d_ws, size_t ws_size,
                              hipStream_t stream) {
    (void)in_sizes; (void)n_in; (void)out_size; (void)ws_size;

    const int*   nodeText   = (const int*)d_in[0];
    const int*   eiTD       = (const int*)d_in[1];
    const int*   eiBU       = (const int*)d_in[2];
    const int*   threadIdxP = (const int*)d_in[3];
    const float* embed_w    = (const float*)d_in[5];
    const float* in_proj_w  = (const float*)d_in[6];
    const float* in_proj_b  = (const float*)d_in[7];
    const float* out_proj_w = (const float*)d_in[8];
    const float* out_proj_b = (const float*)d_in[9];
    const float* s2v_w      = (const float*)d_in[10];
    const float* s2v_b      = (const float*)d_in[11];
    const float* td_w1      = (const float*)d_in[12];
    const float* td_b1      = (const float*)d_in[13];
    const float* td_w2      = (const float*)d_in[14];
    const float* td_b2      = (const float*)d_in[15];
    const float* bu_w1      = (const float*)d_in[16];
    const float* bu_b1      = (const float*)d_in[17];
    const float* bu_w2      = (const float*)d_in[18];
    const float* bu_b2      = (const float*)d_in[19];
    const float* fc_w       = (const float*)d_in[20];
    const float* fc_b       = (const float*)d_in[21];
    float* outp = (float*)d_out;

    // workspace layout
    char* w = (char*)d_ws;
    int*   deg    = (int*)w;                                          // 16384 B
    float* msum   = (float*)(w + 16384);                              // 2048 B
    float* rootv  = (float*)(w + 16384 + 2048);
    float* c1root = (float*)(w + 16384 + 4096);
    float* s2v    = (float*)(w + 24576);                              // 2 MB
    float* hbuf   = (float*)(w + 24576 + 2097152);                    // 4 MB
    float* cbuf   = (float*)(w + 24576 + 2097152 + 4194304);          // 4 MB
    float* Qbuf   = (float*)(w + 24576 + 2097152 + 4194304 + 4194304);             // 2.46 MB
    float* uebuf  = (float*)(w + 24576 + 2097152 + 4194304 + 4194304 + 2457600);   // 12.29 MB

    // folded-weight buffers alias hbuf/cbuf (consumed before k_gemm1/k_gemm2 write them)
    float* WfoldT = hbuf;                 // 1500*256 floats = 1.536 MB (transposed)
    float* WsWo   = cbuf;                 // 256*300
    float* bias3A = cbuf + 76800;         // 256
    float* bpart  = cbuf + 77056;         // 5*256
    float* WqT    = cbuf + 78336;         // 300*300 = 90000 floats (ends at 168336 < 1M)

    hipMemsetAsync(d_ws, 0, 16384 + 2048, stream);

    // ---- independent prep ----
    k_deg<<<dim3((NEDGE + 255) / 256, 2), 256, 0, stream>>>(eiTD, eiBU, deg);
    k_wfoldA<<<16, 320, 0, stream>>>(s2v_w, out_proj_w, out_proj_b, s2v_b, WsWo, bias3A);
    k_wfold2<<<dim3(16, 5), 320, 0, stream>>>(WsWo, in_proj_w, in_proj_b, WfoldT, bpart);
    k_wqT<<<(W2V * W2V + 255) / 256, 256, 0, stream>>>(in_proj_w, WqT);

    // ---- stage 1 ----
    k_q  <<<NPOSTS / 8, 900, 0, stream>>>(nodeText, embed_w, WqT, in_proj_b, Qbuf);
    k_u  <<<dim3(NPOSTS / 16, 5), 320, 0, stream>>>(Qbuf, in_proj_w, uebuf);
    k_att<<<NPOSTS / 2, 512, 0, stream>>>(nodeText, embed_w, uebuf);
    k_s2v<<<NPOSTS / 8, 768, 0, stream>>>(uebuf, WfoldT, bias3A, bpart, s2v);

    // ---- stage 2 ----
    k_gemm1<<<dim3(NPOSTS / 16, 2), 256, 0, stream>>>(s2v, td_w1, bu_w1, td_b1, bu_b1, deg,
                                                      hbuf, cbuf);
    k_scat<<<dim3(NEDGE, 2), 256, 0, stream>>>(eiTD, eiBU, hbuf, deg, cbuf);

    k_root<<<dim3(1, 2), 256, 0, stream>>>(s2v, cbuf, td_w2, bu_w2, threadIdxP, rootv, c1root);

    k_gemm2<<<dim3(NPOSTS / 16, 2), 256, 0, stream>>>(cbuf, td_w2, bu_w2, td_b2, bu_b2, deg,
                                                      rootv, hbuf, cbuf);
    k_scat<<<dim3(NEDGE, 2), 256, 0, stream>>>(eiTD, eiBU, hbuf, deg, cbuf);

    k_reduce<<<dim3(NPOSTS / 32, 2), 256, 0, stream>>>(cbuf, msum);

    k_final<<<1, 256, 0, stream>>>(c1root, msum, fc_w, fc_b, outp);
}

// Round 8
// 365.288 us; speedup vs baseline: 1.0479x; 1.0479x over previous
//
#include <hip/hip_runtime.h>

#define NPOSTS 2048
#define SEQ 64
#define W2V 300
#define NH 5
#define HD 60
#define S2VD 256
#define HIDD 256
#define NEDGE 2047
#define UDIM 1500

#define GLOAD_LDS(g, l) \
    __builtin_amdgcn_global_load_lds((const __attribute__((address_space(1))) void*)(g), \
                                     (__attribute__((address_space(3))) void*)(l), 16, 0, 0)

// ================= Stage 0a: WsWo = Ws@Wo [256x300]; bias3A = bs + Ws@bo =================
__global__ __launch_bounds__(320) void k_wfoldA(
    const float* __restrict__ Ws, const float* __restrict__ Wo,
    const float* __restrict__ bo, const float* __restrict__ bs,
    float* __restrict__ WsWo, float* __restrict__ bias3A)
{
    const int r0 = blockIdx.x * 16;
    const int tid = threadIdx.x;
    __shared__ float sT[W2V][16];   // sT[k][r] = Ws[r0+r][k]
    for (int i = tid; i < 16 * W2V; i += 320) {
        int r = i / W2V, k = i % W2V;
        sT[k][r] = Ws[(size_t)(r0 + r) * W2V + k];
    }
    __syncthreads();
    if (tid <= W2V) {
        float a[16];
        #pragma unroll
        for (int r = 0; r < 16; ++r) a[r] = 0.f;
        for (int k = 0; k < W2V; ++k) {
            float wv = (tid < W2V) ? Wo[(size_t)k * W2V + tid] : bo[k];
            const float4* s4 = reinterpret_cast<const float4*>(&sT[k][0]);
            float4 q0 = s4[0], q1 = s4[1], q2 = s4[2], q3 = s4[3];
            float qq[16] = {q0.x,q0.y,q0.z,q0.w, q1.x,q1.y,q1.z,q1.w,
                            q2.x,q2.y,q2.z,q2.w, q3.x,q3.y,q3.z,q3.w};
            #pragma unroll
            for (int r = 0; r < 16; ++r) a[r] = fmaf(wv, qq[r], a[r]);
        }
        if (tid < W2V) {
            #pragma unroll
            for (int r = 0; r < 16; ++r) WsWo[(size_t)(r0 + r) * W2V + tid] = a[r];
        } else {
            #pragma unroll
            for (int r = 0; r < 16; ++r) bias3A[r0 + r] = bs[r0 + r] + a[r];
        }
    }
}

// ===== Stage 0b: WfoldT[h*300+c][t] = sum_d WsWo[t][h*60+d]*Wv[600+h*60+d][c]; bpart = WsWo_h@bv_h =====
__global__ __launch_bounds__(320) void k_wfold2(
    const float* __restrict__ WsWo, const float* __restrict__ Wqkv, const float* __restrict__ bqkv,
    float* __restrict__ WfoldT, float* __restrict__ bpart)
{
    const int r0 = blockIdx.x * 16;
    const int h = blockIdx.y;
    const int tid = threadIdx.x;
    __shared__ float sT[HD][16];    // sT[d][r] = WsWo[r0+r][h*60+d]
    for (int i = tid; i < 16 * HD; i += 320) {
        int r = i / HD, d = i % HD;
        sT[d][r] = WsWo[(size_t)(r0 + r) * W2V + h * HD + d];
    }
    __syncthreads();
    if (tid <= W2V) {
        float a[16];
        #pragma unroll
        for (int r = 0; r < 16; ++r) a[r] = 0.f;
        for (int d = 0; d < HD; ++d) {
            float wv = (tid < W2V) ? Wqkv[(size_t)(2 * W2V + h * HD + d) * W2V + tid]
                                   : bqkv[2 * W2V + h * HD + d];
            const float4* s4 = reinterpret_cast<const float4*>(&sT[d][0]);
            float4 q0 = s4[0], q1 = s4[1], q2 = s4[2], q3 = s4[3];
            float qq[16] = {q0.x,q0.y,q0.z,q0.w, q1.x,q1.y,q1.z,q1.w,
                            q2.x,q2.y,q2.z,q2.w, q3.x,q3.y,q3.z,q3.w};
            #pragma unroll
            for (int r = 0; r < 16; ++r) a[r] = fmaf(wv, qq[r], a[r]);
        }
        if (tid < W2V) {
            // transposed store: WfoldT[k][t], k = h*300 + tid, t = r0+r
            #pragma unroll
            for (int r = 0; r < 16; ++r)
                WfoldT[(size_t)(h * W2V + tid) * S2VD + (r0 + r)] = a[r];
        } else {
            #pragma unroll
            for (int r = 0; r < 16; ++r) bpart[h * S2VD + r0 + r] = a[r];
        }
    }
}

// ================= Stage 1a: Q = Emb0 @ Wq^T + bq  (8 posts/block)  [R6-proven] =================
__global__ __launch_bounds__(320) void k_q(
    const int* __restrict__ nodeText, const float* __restrict__ embed_w,
    const float* __restrict__ Wqkv, const float* __restrict__ bqkv,
    float* __restrict__ Qout)
{
    const int r0 = blockIdx.x * 8;
    const int tid = threadIdx.x;
    __shared__ int stok[8];
    __shared__ float sE[8][W2V];
    if (tid < 8) stok[tid] = nodeText[(size_t)(r0 + tid) * SEQ];
    __syncthreads();
    for (int i = tid; i < 8 * 75; i += 320) {
        int r = i / 75, c4 = i % 75;
        *reinterpret_cast<float4*>(&sE[r][c4 * 4]) =
            *reinterpret_cast<const float4*>(embed_w + (size_t)stok[r] * W2V + c4 * 4);
    }
    __syncthreads();
    if (tid < W2V) {
        const float4* w4p = reinterpret_cast<const float4*>(Wqkv + (size_t)tid * W2V);
        float b = bqkv[tid];
        float a[8];
        #pragma unroll
        for (int r = 0; r < 8; ++r) a[r] = b;
        for (int c4 = 0; c4 < 75; ++c4) {
            float4 w4 = w4p[c4];
            #pragma unroll
            for (int r = 0; r < 8; ++r) {
                float4 v = *reinterpret_cast<const float4*>(&sE[r][c4 * 4]);
                a[r] = fmaf(w4.x, v.x, a[r]);
                a[r] = fmaf(w4.y, v.y, a[r]);
                a[r] = fmaf(w4.z, v.z, a[r]);
                a[r] = fmaf(w4.w, v.w, a[r]);
            }
        }
        #pragma unroll
        for (int r = 0; r < 8; ++r) Qout[(size_t)(r0 + r) * W2V + tid] = a[r];
    }
}

// ================= Stage 1b: u[p][h*300+c] = sum_d Q[p][h*60+d] * Wk[300+h*60+d][c] =================
__global__ __launch_bounds__(320) void k_u(
    const float* __restrict__ Q, const float* __restrict__ Wqkv, float* __restrict__ uout)
{
    const int r0 = blockIdx.x * 16;
    const int h = blockIdx.y;
    const int tid = threadIdx.x;
    __shared__ float sT[HD][16];   // sT[d][r] = Q[r0+r][h*60+d]
    for (int i = tid; i < 16 * HD; i += 320) {
        int r = i / HD, d = i % HD;
        sT[d][r] = Q[(size_t)(r0 + r) * W2V + h * HD + d];
    }
    __syncthreads();
    if (tid < W2V) {
        float a[16];
        #pragma unroll
        for (int r = 0; r < 16; ++r) a[r] = 0.f;
        for (int d = 0; d < HD; ++d) {
            float wv = Wqkv[(size_t)(W2V + h * HD + d) * W2V + tid];   // coalesced
            const float4* s4 = reinterpret_cast<const float4*>(&sT[d][0]);
            float4 q0 = s4[0], q1 = s4[1], q2 = s4[2], q3 = s4[3];
            float qq[16] = {q0.x,q0.y,q0.z,q0.w, q1.x,q1.y,q1.z,q1.w,
                            q2.x,q2.y,q2.z,q2.w, q3.x,q3.y,q3.z,q3.w};
            #pragma unroll
            for (int r = 0; r < 16; ++r) a[r] = fmaf(wv, qq[r], a[r]);
        }
        #pragma unroll
        for (int r = 0; r < 16; ++r)
            uout[(size_t)(r0 + r) * UDIM + h * W2V + tid] = a[r];
    }
}

// ===== Stage 1c: scores + softmax + e; 1 post/block, DMA staging, 2-way-conflict score reads =====
__global__ __launch_bounds__(256) void k_att(
    const int* __restrict__ nodeText, const float* __restrict__ embed_w,
    float* __restrict__ ue)
{
    __shared__ float sE[SEQ * W2V];      // 76800 B linear (DMA dest)
    __shared__ float satt[NH][SEQ];      // 1280 B
    __shared__ int   stoks[SEQ];         // 256 B

    const int p = blockIdx.x;
    const int tid = threadIdx.x;
    const int wave = tid >> 6, lane = tid & 63;

    if (tid < SEQ) stoks[tid] = nodeText[(size_t)p * SEQ + tid];
    __syncthreads();

    // async DMA: 4800 float4 chunks; chunk i -> sE[4i..4i+3]; 18 full sweeps + 192-tail
    #pragma unroll 3
    for (int it = 0; it < 18; ++it) {
        int i = it * 256 + tid;
        int row = i / 75, c4 = i - row * 75;
        const float* src = embed_w + (size_t)stoks[row] * W2V + c4 * 4;
        GLOAD_LDS(src, &sE[i * 4]);
    }
    if (wave < 3) {   // tail: 192 chunks, wave-uniform predicate
        int i = 18 * 256 + tid;
        int row = i / 75, c4 = i - row * 75;
        const float* src = embed_w + (size_t)stoks[row] * W2V + c4 * 4;
        GLOAD_LDS(src, &sE[i * 4]);
    }
    asm volatile("s_waitcnt vmcnt(0)" ::: "memory");
    __syncthreads();

    // scores: wave w -> head w (+ wave0 -> head4); lane = (tok_lo, cg): 16 toks x 4 col-groups
    // bank check: lanes l, l+32 differ by 8 rows = 2400 dwords == 0 mod 32 -> 2-way only (free)
    const float SC = 0.12909944487358056f;  // 60^-0.5
    const int tokl = lane >> 2, cg = lane & 3;
    for (int h = wave; h < NH; h += 4) {
        const float4* u4 = reinterpret_cast<const float4*>(ue + (size_t)p * UDIM + h * W2V);
        #pragma unroll
        for (int tb = 0; tb < 4; ++tb) {
            const int tok = tb * 16 + tokl;
            const float4* er = reinterpret_cast<const float4*>(&sE[tok * W2V]);
            float acc = 0.f;
            for (int c4 = cg; c4 < 75; c4 += 4) {   // 19 or 18 iters
                float4 uv = u4[c4];
                float4 ev = er[c4];
                acc = fmaf(uv.x, ev.x, acc);
                acc = fmaf(uv.y, ev.y, acc);
                acc = fmaf(uv.z, ev.z, acc);
                acc = fmaf(uv.w, ev.w, acc);
            }
            acc += __shfl_xor(acc, 1);
            acc += __shfl_xor(acc, 2);
            if (cg == 0) satt[h][tok] = acc * SC;
        }
    }
    __syncthreads();

    // softmax per head (scores |s|<<1 -> exp safe without max-subtract)
    for (int h = wave; h < NH; h += 4) {
        float ex = expf(satt[h][lane]);
        float l = ex;
        #pragma unroll
        for (int off = 32; off > 0; off >>= 1) l += __shfl_xor(l, off);
        satt[h][lane] = ex / l;
        // no race: each (h,lane) slot read/written by exactly this lane between barriers
    }
    __syncthreads();

    // e[h][c] = sum_j att[h][j] * Emb[j][c]; 375 float4 tasks
    for (int t = tid; t < NH * 75; t += 256) {
        int h = t / 75, c4 = t - h * 75;
        const float* att = &satt[h][0];
        const float4* eb = reinterpret_cast<const float4*>(&sE[c4 * 4]);  // + j*75 float4s
        float4 a = make_float4(0.f, 0.f, 0.f, 0.f);
        #pragma unroll 4
        for (int j = 0; j < SEQ; ++j) {
            float av = att[j];
            float4 ev = eb[j * 75];
            a.x = fmaf(av, ev.x, a.x);
            a.y = fmaf(av, ev.y, a.y);
            a.z = fmaf(av, ev.z, a.z);
            a.w = fmaf(av, ev.w, a.w);
        }
        *reinterpret_cast<float4*>(ue + (size_t)p * UDIM + h * W2V + c4 * 4) = a;
    }
}

// ===== Stage 1d: s2v = tanh(W @ e + bias3); tiled GEMM 16 posts x 64 dims, grid 512 =====
__global__ __launch_bounds__(256) void k_s2v(
    const float* __restrict__ e, const float* __restrict__ WfoldT,
    const float* __restrict__ bias3A, const float* __restrict__ bpart,
    float* __restrict__ s2v_out)
{
    __shared__ float se[16][W2V];   // 19200 B per chunk
    const int p0 = (blockIdx.x >> 2) * 16;   // 128 post tiles
    const int d0 = (blockIdx.x & 3) * 64;    // 4 dim tiles
    const int tid = threadIdx.x;
    const int d = tid & 63;        // lane = dim -> coalesced weights
    const int pg = tid >> 6;       // wave = post-group -> uniform LDS broadcast

    float a0 = 0.f, a1 = 0.f, a2 = 0.f, a3 = 0.f;
    for (int ch = 0; ch < 5; ++ch) {
        __syncthreads();
        for (int i = tid; i < 16 * 75; i += 256) {
            int r = i / 75, c4 = i - r * 75;
            *reinterpret_cast<float4*>(&se[r][c4 * 4]) =
                *reinterpret_cast<const float4*>(e + (size_t)(p0 + r) * UDIM + ch * W2V + c4 * 4);
        }
        __syncthreads();
        const float* wp = WfoldT + (size_t)(ch * W2V) * S2VD + d0 + d;
        const float* r0p = &se[pg * 4 + 0][0];
        const float* r1p = &se[pg * 4 + 1][0];
        const float* r2p = &se[pg * 4 + 2][0];
        const float* r3p = &se[pg * 4 + 3][0];
        for (int k4 = 0; k4 < 75; ++k4) {
            const float w0 = wp[(size_t)(4 * k4 + 0) * S2VD];
            const float w1 = wp[(size_t)(4 * k4 + 1) * S2VD];
            const float w2 = wp[(size_t)(4 * k4 + 2) * S2VD];
            const float w3 = wp[(size_t)(4 * k4 + 3) * S2VD];
            const float4 e0 = *reinterpret_cast<const float4*>(r0p + k4 * 4);
            const float4 e1 = *reinterpret_cast<const float4*>(r1p + k4 * 4);
            const float4 e2 = *reinterpret_cast<const float4*>(r2p + k4 * 4);
            const float4 e3 = *reinterpret_cast<const float4*>(r3p + k4 * 4);
            a0 = fmaf(w0, e0.x, a0); a0 = fmaf(w1, e0.y, a0); a0 = fmaf(w2, e0.z, a0); a0 = fmaf(w3, e0.w, a0);
            a1 = fmaf(w0, e1.x, a1); a1 = fmaf(w1, e1.y, a1); a1 = fmaf(w2, e1.z, a1); a1 = fmaf(w3, e1.w, a1);
            a2 = fmaf(w0, e2.x, a2); a2 = fmaf(w1, e2.y, a2); a2 = fmaf(w2, e2.z, a2); a2 = fmaf(w3, e2.w, a2);
            a3 = fmaf(w0, e3.x, a3); a3 = fmaf(w1, e3.y, a3); a3 = fmaf(w2, e3.z, a3); a3 = fmaf(w3, e3.w, a3);
        }
    }
    const int t = d0 + d;
    const float bias = bias3A[t] + bpart[t] + bpart[256 + t] + bpart[512 + t]
                     + bpart[768 + t] + bpart[1024 + t];
    const int pr = p0 + pg * 4;
    s2v_out[(size_t)(pr + 0) * S2VD + t] = tanhf(a0 + bias);
    s2v_out[(size_t)(pr + 1) * S2VD + t] = tanhf(a1 + bias);
    s2v_out[(size_t)(pr + 2) * S2VD + t] = tanhf(a2 + bias);
    s2v_out[(size_t)(pr + 3) * S2VD + t] = tanhf(a3 + bias);
}

// ================= Stage 2: GCN branches (blockIdx.y = branch: 0=TD, 1=BU) =================

__global__ __launch_bounds__(256) void k_deg(
    const int* __restrict__ eiTD, const int* __restrict__ eiBU, int* __restrict__ deg)
{
    const int b = blockIdx.y;
    const int* ei = b ? eiBU : eiTD;
    int e = blockIdx.x * 256 + threadIdx.x;
    if (e < NEDGE) atomicAdd(&deg[b * NPOSTS + ei[NEDGE + e]], 1);
}

__global__ __launch_bounds__(256) void k_gemm1(
    const float* __restrict__ x, const float* __restrict__ wtd, const float* __restrict__ wbu,
    const float* __restrict__ btd, const float* __restrict__ bbu, const int* __restrict__ deg,
    float* __restrict__ hout, float* __restrict__ cout_)
{
    const int b = blockIdx.y;
    const float* w = b ? wbu : wtd;
    const float* bias = b ? bbu : btd;
    float* hb = hout + (size_t)b * NPOSTS * HIDD;
    float* cb = cout_ + (size_t)b * NPOSTS * HIDD;
    const int* dg = deg + b * NPOSTS;
    const int r0 = blockIdx.x * 16;
    const int tid = threadIdx.x;
    __shared__ float sx[16][S2VD];
    for (int i = tid; i < 16 * S2VD; i += 256)
        sx[i / S2VD][i % S2VD] = x[(size_t)(r0 + i / S2VD) * S2VD + (i % S2VD)];
    __syncthreads();
    float acc[16];
    #pragma unroll
    for (int r = 0; r < 16; ++r) acc[r] = 0.f;
    const float4* wr4 = reinterpret_cast<const float4*>(w + (size_t)tid * S2VD);
    for (int c4 = 0; c4 < 64; ++c4) {
        float4 w4 = wr4[c4];
        #pragma unroll
        for (int r = 0; r < 16; ++r) {
            const float4 v = *reinterpret_cast<const float4*>(&sx[r][c4 * 4]);
            acc[r] = fmaf(w4.x, v.x, acc[r]);
            acc[r] = fmaf(w4.y, v.y, acc[r]);
            acc[r] = fmaf(w4.z, v.z, acc[r]);
            acc[r] = fmaf(w4.w, v.w, acc[r]);
        }
    }
    float bv = bias[tid];
    #pragma unroll
    for (int r = 0; r < 16; ++r) {
        int n = r0 + r;
        float dinv = 1.f / (float)(dg[n] + 1);
        hb[(size_t)n * HIDD + tid] = acc[r];
        cb[(size_t)n * HIDD + tid] = bv + acc[r] * dinv;
    }
}

__global__ __launch_bounds__(256) void k_gemm2(
    const float* __restrict__ c1, const float* __restrict__ w2td, const float* __restrict__ w2bu,
    const float* __restrict__ btd, const float* __restrict__ bbu, const int* __restrict__ deg,
    const float* __restrict__ rootv, float* __restrict__ hout, float* __restrict__ cout_)
{
    const int b = blockIdx.y;
    const float* w = b ? w2bu : w2td;
    const float* bias = b ? bbu : btd;
    const float* xin = c1 + (size_t)b * NPOSTS * HIDD;
    float* hb = hout + (size_t)b * NPOSTS * HIDD;
    float* cb = cout_ + (size_t)b * NPOSTS * HIDD;
    const int* dg = deg + b * NPOSTS;
    const int r0 = blockIdx.x * 16;
    const int tid = threadIdx.x;
    __shared__ float sx[16][HIDD];
    for (int i = tid; i < 16 * HIDD; i += 256)
        sx[i / HIDD][i % HIDD] = fmaxf(xin[(size_t)(r0 + i / HIDD) * HIDD + (i % HIDD)], 0.f);
    __syncthreads();
    float acc[16];
    const float rv = rootv[b * HIDD + tid];
    #pragma unroll
    for (int r = 0; r < 16; ++r) acc[r] = rv;
    const float4* wr4 = reinterpret_cast<const float4*>(w + (size_t)tid * 512);
    for (int c4 = 0; c4 < 64; ++c4) {
        float4 w4 = wr4[c4];
        #pragma unroll
        for (int r = 0; r < 16; ++r) {
            const float4 v = *reinterpret_cast<const float4*>(&sx[r][c4 * 4]);
            acc[r] = fmaf(w4.x, v.x, acc[r]);
            acc[r] = fmaf(w4.y, v.y, acc[r]);
            acc[r] = fmaf(w4.z, v.z, acc[r]);
            acc[r] = fmaf(w4.w, v.w, acc[r]);
        }
    }
    float bv = bias[tid];
    #pragma unroll
    for (int r = 0; r < 16; ++r) {
        int n = r0 + r;
        float dinv = 1.f / (float)(dg[n] + 1);
        hb[(size_t)n * HIDD + tid] = acc[r];
        cb[(size_t)n * HIDD + tid] = bv + acc[r] * dinv;
    }
}

__global__ __launch_bounds__(256) void k_scat(
    const int* __restrict__ eiTD, const int* __restrict__ eiBU,
    const float* __restrict__ h, const int* __restrict__ deg, float* __restrict__ cacc)
{
    const int b = blockIdx.y, e = blockIdx.x, tid = threadIdx.x;
    const int* ei = b ? eiBU : eiTD;
    const int s = ei[e], d = ei[NEDGE + e];
    const int* dg = deg + b * NPOSTS;
    float norm = rsqrtf((float)(dg[s] + 1)) * rsqrtf((float)(dg[d] + 1));
    const float* hb = h + (size_t)b * NPOSTS * HIDD;
    float* cb = cacc + (size_t)b * NPOSTS * HIDD;
    atomicAdd(&cb[(size_t)d * HIDD + tid], norm * hb[(size_t)s * HIDD + tid]);
}

__global__ __launch_bounds__(256) void k_root(
    const float* __restrict__ s2v, const float* __restrict__ c1,
    const float* __restrict__ w2td, const float* __restrict__ w2bu,
    const int* __restrict__ rootPtr, float* __restrict__ rootv, float* __restrict__ c1root)
{
    const int b = blockIdx.y, tid = threadIdx.x;
    const float* w2 = b ? w2bu : w2td;
    const int root = rootPtr[0];
    __shared__ float sx[S2VD];
    sx[tid] = fmaxf(s2v[(size_t)root * S2VD + tid], 0.f);
    __syncthreads();
    const float* cb = c1 + (size_t)b * NPOSTS * HIDD;
    c1root[b * HIDD + tid] = cb[(size_t)root * HIDD + tid];
    const float* wr = w2 + (size_t)tid * 512 + 256;
    float acc = 0.f;
    #pragma unroll 4
    for (int c = 0; c < S2VD; ++c) acc = fmaf(wr[c], sx[c], acc);
    rootv[b * HIDD + tid] = acc;
}

__global__ __launch_bounds__(256) void k_reduce(
    const float* __restrict__ cacc, float* __restrict__ msum)
{
    const int b = blockIdx.y, tid = threadIdx.x;
    const int base = blockIdx.x * 32;
    const float* cb = cacc + (size_t)b * NPOSTS * HIDD;
    float local = 0.f;
    #pragma unroll 4
    for (int r = 0; r < 32; ++r) local += fmaxf(cb[(size_t)(base + r) * HIDD + tid], 0.f);
    atomicAdd(&msum[b * HIDD + tid], local);
}

__global__ __launch_bounds__(256) void k_final(
    const float* __restrict__ c1root, const float* __restrict__ msum,
    const float* __restrict__ fc_w, const float* __restrict__ fc_b, float* __restrict__ outp)
{
    const int tid = threadIdx.x;
    __shared__ float sf[1024];
    for (int k = tid; k < 1024; k += 256) {
        int seg = k >> 8, idx = k & 255;
        float v;
        if (seg == 0)      v = c1root[idx];
        else if (seg == 1) v = msum[idx] * (1.f / (float)NPOSTS);
        else if (seg == 2) v = c1root[256 + idx];
        else               v = msum[256 + idx] * (1.f / (float)NPOSTS);
        sf[k] = v;
    }
    __syncthreads();
    const int t = tid >> 6, lane = tid & 63;
    float part = 0.f;
    for (int k = lane; k < 1024; k += 64) part = fmaf(fc_w[t * 1024 + k], sf[k], part);
    #pragma unroll
    for (int off = 32; off > 0; off >>= 1) part += __shfl_down(part, off);
    if (lane == 0) outp[t] = part + fc_b[t];
}

extern "C" void kernel_launch(void* const* d_in, const int* in_sizes, int n_in,
                              void* d_out, int out_size, void* d_ws, size_t ws_size,
                              hipStream_t stream) {
    (void)in_sizes; (void)n_in; (void)out_size; (void)ws_size;

    const int*   nodeText   = (const int*)d_in[0];
    const int*   eiTD       = (const int*)d_in[1];
    const int*   eiBU       = (const int*)d_in[2];
    const int*   threadIdxP = (const int*)d_in[3];
    const float* embed_w    = (const float*)d_in[5];
    const float* in_proj_w  = (const float*)d_in[6];
    const float* in_proj_b  = (const float*)d_in[7];
    const float* out_proj_w = (const float*)d_in[8];
    const float* out_proj_b = (const float*)d_in[9];
    const float* s2v_w      = (const float*)d_in[10];
    const float* s2v_b      = (const float*)d_in[11];
    const float* td_w1      = (const float*)d_in[12];
    const float* td_b1      = (const float*)d_in[13];
    const float* td_w2      = (const float*)d_in[14];
    const float* td_b2      = (const float*)d_in[15];
    const float* bu_w1      = (const float*)d_in[16];
    const float* bu_b1      = (const float*)d_in[17];
    const float* bu_w2      = (const float*)d_in[18];
    const float* bu_b2      = (const float*)d_in[19];
    const float* fc_w       = (const float*)d_in[20];
    const float* fc_b       = (const float*)d_in[21];
    float* outp = (float*)d_out;

    // workspace layout
    char* w = (char*)d_ws;
    int*   deg    = (int*)w;                                          // 16384 B
    float* msum   = (float*)(w + 16384);                              // 2048 B
    float* rootv  = (float*)(w + 16384 + 2048);
    float* c1root = (float*)(w + 16384 + 4096);
    float* s2v    = (float*)(w + 24576);                              // 2 MB
    float* hbuf   = (float*)(w + 24576 + 2097152);                    // 4 MB
    float* cbuf   = (float*)(w + 24576 + 2097152 + 4194304);          // 4 MB
    float* Qbuf   = (float*)(w + 24576 + 2097152 + 4194304 + 4194304);             // 2.46 MB
    float* uebuf  = (float*)(w + 24576 + 2097152 + 4194304 + 4194304 + 2457600);   // 12.29 MB

    // folded-weight buffers alias hbuf/cbuf (consumed before k_gemm1/k_gemm2 write them)
    float* WfoldT = hbuf;                 // 1500*256 floats = 1.536 MB (transposed)
    float* WsWo   = cbuf;                 // 256*300
    float* bias3A = cbuf + 76800;         // 256
    float* bpart  = cbuf + 77056;         // 5*256

    hipMemsetAsync(d_ws, 0, 16384 + 2048, stream);

    // ---- independent prep ----
    k_deg<<<dim3((NEDGE + 255) / 256, 2), 256, 0, stream>>>(eiTD, eiBU, deg);
    k_wfoldA<<<16, 320, 0, stream>>>(s2v_w, out_proj_w, out_proj_b, s2v_b, WsWo, bias3A);
    k_wfold2<<<dim3(16, 5), 320, 0, stream>>>(WsWo, in_proj_w, in_proj_b, WfoldT, bpart);

    // ---- stage 1 ----
    k_q  <<<NPOSTS / 8, 320, 0, stream>>>(nodeText, embed_w, in_proj_w, in_proj_b, Qbuf);
    k_u  <<<dim3(NPOSTS / 16, 5), 320, 0, stream>>>(Qbuf, in_proj_w, uebuf);
    k_att<<<NPOSTS, 256, 0, stream>>>(nodeText, embed_w, uebuf);
    k_s2v<<<512, 256, 0, stream>>>(uebuf, WfoldT, bias3A, bpart, s2v);

    // ---- stage 2 ----
    k_gemm1<<<dim3(NPOSTS / 16, 2), 256, 0, stream>>>(s2v, td_w1, bu_w1, td_b1, bu_b1, deg,
                                                      hbuf, cbuf);
    k_scat<<<dim3(NEDGE, 2), 256, 0, stream>>>(eiTD, eiBU, hbuf, deg, cbuf);

    k_root<<<dim3(1, 2), 256, 0, stream>>>(s2v, cbuf, td_w2, bu_w2, threadIdxP, rootv, c1root);

    k_gemm2<<<dim3(NPOSTS / 16, 2), 256, 0, stream>>>(cbuf, td_w2, bu_w2, td_b2, bu_b2, deg,
                                                      rootv, hbuf, cbuf);
    k_scat<<<dim3(NEDGE, 2), 256, 0, stream>>>(eiTD, eiBU, hbuf, deg, cbuf);

    k_reduce<<<dim3(NPOSTS / 32, 2), 256, 0, stream>>>(cbuf, msum);

    k_final<<<1, 256, 0, stream>>>(c1root, msum, fc_w, fc_b, outp);
}

// Round 9
// 333.156 us; speedup vs baseline: 1.1490x; 1.0964x over previous
//
#include <hip/hip_runtime.h>

#define NPOSTS 2048
#define SEQ 64
#define W2V 300
#define NH 5
#define HD 60
#define S2VD 256
#define HIDD 256
#define NEDGE 2047
#define UDIM 1500

#define GLOAD_LDS(g, l) \
    __builtin_amdgcn_global_load_lds((const __attribute__((address_space(1))) void*)(g), \
                                     (__attribute__((address_space(3))) void*)(l), 16, 0, 0)

__device__ __forceinline__ float dot4(float4 a, float4 b) {
    return fmaf(a.x, b.x, fmaf(a.y, b.y, fmaf(a.z, b.z, a.w * b.w)));
}

// ================= Stage 0a: WsWo = Ws@Wo [256x300]; bias3A = bs + Ws@bo =================
__global__ __launch_bounds__(320) void k_wfoldA(
    const float* __restrict__ Ws, const float* __restrict__ Wo,
    const float* __restrict__ bo, const float* __restrict__ bs,
    float* __restrict__ WsWo, float* __restrict__ bias3A)
{
    const int r0 = blockIdx.x * 16;
    const int tid = threadIdx.x;
    __shared__ float sT[W2V][16];   // sT[k][r] = Ws[r0+r][k]
    for (int i = tid; i < 16 * W2V; i += 320) {
        int r = i / W2V, k = i % W2V;
        sT[k][r] = Ws[(size_t)(r0 + r) * W2V + k];
    }
    __syncthreads();
    if (tid <= W2V) {
        float a[16];
        #pragma unroll
        for (int r = 0; r < 16; ++r) a[r] = 0.f;
        for (int k = 0; k < W2V; ++k) {
            float wv = (tid < W2V) ? Wo[(size_t)k * W2V + tid] : bo[k];
            const float4* s4 = reinterpret_cast<const float4*>(&sT[k][0]);
            float4 q0 = s4[0], q1 = s4[1], q2 = s4[2], q3 = s4[3];
            float qq[16] = {q0.x,q0.y,q0.z,q0.w, q1.x,q1.y,q1.z,q1.w,
                            q2.x,q2.y,q2.z,q2.w, q3.x,q3.y,q3.z,q3.w};
            #pragma unroll
            for (int r = 0; r < 16; ++r) a[r] = fmaf(wv, qq[r], a[r]);
        }
        if (tid < W2V) {
            #pragma unroll
            for (int r = 0; r < 16; ++r) WsWo[(size_t)(r0 + r) * W2V + tid] = a[r];
        } else {
            #pragma unroll
            for (int r = 0; r < 16; ++r) bias3A[r0 + r] = bs[r0 + r] + a[r];
        }
    }
}

// ===== Stage 0b: WfoldT[h*300+c][t] = sum_d WsWo[t][h*60+d]*Wv[600+h*60+d][c]; bpart = WsWo_h@bv_h =====
__global__ __launch_bounds__(320) void k_wfold2(
    const float* __restrict__ WsWo, const float* __restrict__ Wqkv, const float* __restrict__ bqkv,
    float* __restrict__ WfoldT, float* __restrict__ bpart)
{
    const int r0 = blockIdx.x * 16;
    const int h = blockIdx.y;
    const int tid = threadIdx.x;
    __shared__ float sT[HD][16];    // sT[d][r] = WsWo[r0+r][h*60+d]
    for (int i = tid; i < 16 * HD; i += 320) {
        int r = i / HD, d = i % HD;
        sT[d][r] = WsWo[(size_t)(r0 + r) * W2V + h * HD + d];
    }
    __syncthreads();
    if (tid <= W2V) {
        float a[16];
        #pragma unroll
        for (int r = 0; r < 16; ++r) a[r] = 0.f;
        for (int d = 0; d < HD; ++d) {
            float wv = (tid < W2V) ? Wqkv[(size_t)(2 * W2V + h * HD + d) * W2V + tid]
                                   : bqkv[2 * W2V + h * HD + d];
            const float4* s4 = reinterpret_cast<const float4*>(&sT[d][0]);
            float4 q0 = s4[0], q1 = s4[1], q2 = s4[2], q3 = s4[3];
            float qq[16] = {q0.x,q0.y,q0.z,q0.w, q1.x,q1.y,q1.z,q1.w,
                            q2.x,q2.y,q2.z,q2.w, q3.x,q3.y,q3.z,q3.w};
            #pragma unroll
            for (int r = 0; r < 16; ++r) a[r] = fmaf(wv, qq[r], a[r]);
        }
        if (tid < W2V) {
            #pragma unroll
            for (int r = 0; r < 16; ++r)
                WfoldT[(size_t)(h * W2V + tid) * S2VD + (r0 + r)] = a[r];
        } else {
            #pragma unroll
            for (int r = 0; r < 16; ++r) bpart[h * S2VD + r0 + r] = a[r];
        }
    }
}

// ================= Stage 1a: Q = Emb0 @ Wq^T + bq  (8 posts/block) =================
__global__ __launch_bounds__(320) void k_q(
    const int* __restrict__ nodeText, const float* __restrict__ embed_w,
    const float* __restrict__ Wqkv, const float* __restrict__ bqkv,
    float* __restrict__ Qout)
{
    const int r0 = blockIdx.x * 8;
    const int tid = threadIdx.x;
    __shared__ int stok[8];
    __shared__ float sE[8][W2V];
    if (tid < 8) stok[tid] = nodeText[(size_t)(r0 + tid) * SEQ];
    __syncthreads();
    for (int i = tid; i < 8 * 75; i += 320) {
        int r = i / 75, c4 = i % 75;
        *reinterpret_cast<float4*>(&sE[r][c4 * 4]) =
            *reinterpret_cast<const float4*>(embed_w + (size_t)stok[r] * W2V + c4 * 4);
    }
    __syncthreads();
    if (tid < W2V) {
        const float4* w4p = reinterpret_cast<const float4*>(Wqkv + (size_t)tid * W2V);
        float b = bqkv[tid];
        float a[8];
        #pragma unroll
        for (int r = 0; r < 8; ++r) a[r] = b;
        for (int c4 = 0; c4 < 75; ++c4) {
            float4 w4 = w4p[c4];
            #pragma unroll
            for (int r = 0; r < 8; ++r) {
                float4 v = *reinterpret_cast<const float4*>(&sE[r][c4 * 4]);
                a[r] = fmaf(w4.x, v.x, a[r]);
                a[r] = fmaf(w4.y, v.y, a[r]);
                a[r] = fmaf(w4.z, v.z, a[r]);
                a[r] = fmaf(w4.w, v.w, a[r]);
            }
        }
        #pragma unroll
        for (int r = 0; r < 8; ++r) Qout[(size_t)(r0 + r) * W2V + tid] = a[r];
    }
}

// ================= Stage 1b: u[p][h*300+c] = sum_d Q[p][h*60+d] * Wk[300+h*60+d][c] =================
__global__ __launch_bounds__(320) void k_u(
    const float* __restrict__ Q, const float* __restrict__ Wqkv, float* __restrict__ uout)
{
    const int r0 = blockIdx.x * 16;
    const int h = blockIdx.y;
    const int tid = threadIdx.x;
    __shared__ float sT[HD][16];   // sT[d][r] = Q[r0+r][h*60+d]
    for (int i = tid; i < 16 * HD; i += 320) {
        int r = i / HD, d = i % HD;
        sT[d][r] = Q[(size_t)(r0 + r) * W2V + h * HD + d];
    }
    __syncthreads();
    if (tid < W2V) {
        float a[16];
        #pragma unroll
        for (int r = 0; r < 16; ++r) a[r] = 0.f;
        for (int d = 0; d < HD; ++d) {
            float wv = Wqkv[(size_t)(W2V + h * HD + d) * W2V + tid];   // coalesced
            const float4* s4 = reinterpret_cast<const float4*>(&sT[d][0]);
            float4 q0 = s4[0], q1 = s4[1], q2 = s4[2], q3 = s4[3];
            float qq[16] = {q0.x,q0.y,q0.z,q0.w, q1.x,q1.y,q1.z,q1.w,
                            q2.x,q2.y,q2.z,q2.w, q3.x,q3.y,q3.z,q3.w};
            #pragma unroll
            for (int r = 0; r < 16; ++r) a[r] = fmaf(wv, qq[r], a[r]);
        }
        #pragma unroll
        for (int r = 0; r < 16; ++r)
            uout[(size_t)(r0 + r) * UDIM + h * W2V + tid] = a[r];
    }
}

// ===== Stage 1c: scores + softmax + e; 1 post/block, 512 thr, min-LDS-traffic design =====
__global__ __launch_bounds__(512) void k_att(
    const int* __restrict__ nodeText, const float* __restrict__ embed_w,
    float* __restrict__ ue)
{
    __shared__ float  sE[SEQ * W2V];        // 76800 B linear (DMA dest)
    __shared__ float  spart[8][NH][SEQ];    // 10240 B score partials (per c4-slice wave)
    __shared__ float  satt[NH][SEQ];        // 1280 B
    __shared__ float4 epart[6][NH][80];     // 38400 B e partials (per token-group)
    __shared__ int    stoks[SEQ];

    const int p = blockIdx.x;
    const int tid = threadIdx.x;
    const int wave = tid >> 6, lane = tid & 63;

    if (tid < SEQ) stoks[tid] = nodeText[(size_t)p * SEQ + tid];
    __syncthreads();

    // ---- async DMA: 4800 float4 chunks (9 sweeps x 512 + 192 tail) ----
    #pragma unroll 3
    for (int it = 0; it < 9; ++it) {
        int i = it * 512 + tid;
        int row = i / 75, c4 = i - row * 75;
        const float* src = embed_w + (size_t)stoks[row] * W2V + c4 * 4;
        GLOAD_LDS(src, &sE[i * 4]);
    }
    if (wave < 3) {   // tail: 192 chunks, wave-uniform predicate
        int i = 9 * 512 + tid;
        int row = i / 75, c4 = i - row * 75;
        const float* src = embed_w + (size_t)stoks[row] * W2V + c4 * 4;
        GLOAD_LDS(src, &sE[i * 4]);
    }
    asm volatile("s_waitcnt vmcnt(0)" ::: "memory");
    __syncthreads();

    // ---- score partials: lane = token, wave w owns c4-slice; 1 gather feeds 5 heads ----
    {
        const int c4s = (wave < 3) ? wave * 10 : 30 + (wave - 3) * 9;
        const int c4e = (wave < 3) ? c4s + 10 : c4s + 9;
        const float* erow = &sE[lane * W2V];
        const float4* up = reinterpret_cast<const float4*>(ue + (size_t)p * UDIM);
        float a0 = 0.f, a1 = 0.f, a2 = 0.f, a3 = 0.f, a4 = 0.f;
        for (int c4 = c4s; c4 < c4e; ++c4) {
            float4 ev = *reinterpret_cast<const float4*>(erow + c4 * 4);  // 8-way gather
            a0 += dot4(ev, up[0 * 75 + c4]);   // u addrs wave-uniform -> s_load
            a1 += dot4(ev, up[1 * 75 + c4]);
            a2 += dot4(ev, up[2 * 75 + c4]);
            a3 += dot4(ev, up[3 * 75 + c4]);
            a4 += dot4(ev, up[4 * 75 + c4]);
        }
        spart[wave][0][lane] = a0;
        spart[wave][1][lane] = a1;
        spart[wave][2][lane] = a2;
        spart[wave][3][lane] = a3;
        spart[wave][4][lane] = a4;
    }
    __syncthreads();

    // ---- reduce partials + softmax: wave h (<5) handles head h, lane = token ----
    if (wave < NH) {
        const int h = wave;
        float s = 0.f;
        #pragma unroll
        for (int w = 0; w < 8; ++w) s += spart[w][h][lane];
        // |score| << 1 (0.02-scale weights) -> exp safe without max-subtract
        float ex = expf(s * 0.12909944487358056f);
        float l = ex;
        #pragma unroll
        for (int off = 32; off > 0; off >>= 1) l += __shfl_xor(l, off);
        satt[h][lane] = ex / l;
    }
    __syncthreads();

    // ---- e partials: task = (token-group jg, c4); 1 contiguous read feeds 5 heads ----
    if (tid < 450) {
        const int jg = tid / 75, c4 = tid - jg * 75;
        const int j0 = jg * 11, j1 = (j0 + 11 < SEQ) ? j0 + 11 : SEQ;
        const float4 z = make_float4(0.f, 0.f, 0.f, 0.f);
        float4 a0 = z, a1 = z, a2 = z, a3 = z, a4 = z;
        for (int j = j0; j < j1; ++j) {
            float4 ev = *reinterpret_cast<const float4*>(&sE[j * W2V + c4 * 4]);
            float w0 = satt[0][j], w1 = satt[1][j], w2 = satt[2][j];
            float w3 = satt[3][j], w4 = satt[4][j];
            a0.x = fmaf(w0, ev.x, a0.x); a0.y = fmaf(w0, ev.y, a0.y); a0.z = fmaf(w0, ev.z, a0.z); a0.w = fmaf(w0, ev.w, a0.w);
            a1.x = fmaf(w1, ev.x, a1.x); a1.y = fmaf(w1, ev.y, a1.y); a1.z = fmaf(w1, ev.z, a1.z); a1.w = fmaf(w1, ev.w, a1.w);
            a2.x = fmaf(w2, ev.x, a2.x); a2.y = fmaf(w2, ev.y, a2.y); a2.z = fmaf(w2, ev.z, a2.z); a2.w = fmaf(w2, ev.w, a2.w);
            a3.x = fmaf(w3, ev.x, a3.x); a3.y = fmaf(w3, ev.y, a3.y); a3.z = fmaf(w3, ev.z, a3.z); a3.w = fmaf(w3, ev.w, a3.w);
            a4.x = fmaf(w4, ev.x, a4.x); a4.y = fmaf(w4, ev.y, a4.y); a4.z = fmaf(w4, ev.z, a4.z); a4.w = fmaf(w4, ev.w, a4.w);
        }
        epart[jg][0][c4] = a0;
        epart[jg][1][c4] = a1;
        epart[jg][2][c4] = a2;
        epart[jg][3][c4] = a3;
        epart[jg][4][c4] = a4;
    }
    __syncthreads();

    // ---- final e reduce: 375 (h,c4) tasks; overwrite u row in global ----
    if (tid < NH * 75) {
        const int h = tid / 75, c4 = tid - h * 75;
        float4 a = epart[0][h][c4];
        #pragma unroll
        for (int jg = 1; jg < 6; ++jg) {
            float4 v = epart[jg][h][c4];
            a.x += v.x; a.y += v.y; a.z += v.z; a.w += v.w;
        }
        *reinterpret_cast<float4*>(ue + (size_t)p * UDIM + h * W2V + c4 * 4) = a;
    }
}

// ===== Stage 1d: s2v = tanh(W @ e + bias3); tiled GEMM 16 posts x 64 dims, grid 512 =====
__global__ __launch_bounds__(256) void k_s2v(
    const float* __restrict__ e, const float* __restrict__ WfoldT,
    const float* __restrict__ bias3A, const float* __restrict__ bpart,
    float* __restrict__ s2v_out)
{
    __shared__ float se[16][W2V];   // 19200 B per chunk
    const int p0 = (blockIdx.x >> 2) * 16;   // 128 post tiles
    const int d0 = (blockIdx.x & 3) * 64;    // 4 dim tiles
    const int tid = threadIdx.x;
    const int d = tid & 63;        // lane = dim -> coalesced weights
    const int pg = tid >> 6;       // wave = post-group -> uniform LDS broadcast

    float a0 = 0.f, a1 = 0.f, a2 = 0.f, a3 = 0.f;
    for (int ch = 0; ch < 5; ++ch) {
        __syncthreads();
        for (int i = tid; i < 16 * 75; i += 256) {
            int r = i / 75, c4 = i - r * 75;
            *reinterpret_cast<float4*>(&se[r][c4 * 4]) =
                *reinterpret_cast<const float4*>(e + (size_t)(p0 + r) * UDIM + ch * W2V + c4 * 4);
        }
        __syncthreads();
        const float* wp = WfoldT + (size_t)(ch * W2V) * S2VD + d0 + d;
        const float* r0p = &se[pg * 4 + 0][0];
        const float* r1p = &se[pg * 4 + 1][0];
        const float* r2p = &se[pg * 4 + 2][0];
        const float* r3p = &se[pg * 4 + 3][0];
        for (int k4 = 0; k4 < 75; ++k4) {
            const float w0 = wp[(size_t)(4 * k4 + 0) * S2VD];
            const float w1 = wp[(size_t)(4 * k4 + 1) * S2VD];
            const float w2 = wp[(size_t)(4 * k4 + 2) * S2VD];
            const float w3 = wp[(size_t)(4 * k4 + 3) * S2VD];
            const float4 e0 = *reinterpret_cast<const float4*>(r0p + k4 * 4);
            const float4 e1 = *reinterpret_cast<const float4*>(r1p + k4 * 4);
            const float4 e2 = *reinterpret_cast<const float4*>(r2p + k4 * 4);
            const float4 e3 = *reinterpret_cast<const float4*>(r3p + k4 * 4);
            a0 = fmaf(w0, e0.x, a0); a0 = fmaf(w1, e0.y, a0); a0 = fmaf(w2, e0.z, a0); a0 = fmaf(w3, e0.w, a0);
            a1 = fmaf(w0, e1.x, a1); a1 = fmaf(w1, e1.y, a1); a1 = fmaf(w2, e1.z, a1); a1 = fmaf(w3, e1.w, a1);
            a2 = fmaf(w0, e2.x, a2); a2 = fmaf(w1, e2.y, a2); a2 = fmaf(w2, e2.z, a2); a2 = fmaf(w3, e2.w, a2);
            a3 = fmaf(w0, e3.x, a3); a3 = fmaf(w1, e3.y, a3); a3 = fmaf(w2, e3.z, a3); a3 = fmaf(w3, e3.w, a3);
        }
    }
    const int t = d0 + d;
    const float bias = bias3A[t] + bpart[t] + bpart[256 + t] + bpart[512 + t]
                     + bpart[768 + t] + bpart[1024 + t];
    const int pr = p0 + pg * 4;
    s2v_out[(size_t)(pr + 0) * S2VD + t] = tanhf(a0 + bias);
    s2v_out[(size_t)(pr + 1) * S2VD + t] = tanhf(a1 + bias);
    s2v_out[(size_t)(pr + 2) * S2VD + t] = tanhf(a2 + bias);
    s2v_out[(size_t)(pr + 3) * S2VD + t] = tanhf(a3 + bias);
}

// ================= Stage 2: GCN branches (blockIdx.y = branch: 0=TD, 1=BU) =================

__global__ __launch_bounds__(256) void k_deg(
    const int* __restrict__ eiTD, const int* __restrict__ eiBU, int* __restrict__ deg)
{
    const int b = blockIdx.y;
    const int* ei = b ? eiBU : eiTD;
    int e = blockIdx.x * 256 + threadIdx.x;
    if (e < NEDGE) atomicAdd(&deg[b * NPOSTS + ei[NEDGE + e]], 1);
}

__global__ __launch_bounds__(256) void k_gemm1(
    const float* __restrict__ x, const float* __restrict__ wtd, const float* __restrict__ wbu,
    const float* __restrict__ btd, const float* __restrict__ bbu, const int* __restrict__ deg,
    float* __restrict__ hout, float* __restrict__ cout_)
{
    const int b = blockIdx.y;
    const float* w = b ? wbu : wtd;
    const float* bias = b ? bbu : btd;
    float* hb = hout + (size_t)b * NPOSTS * HIDD;
    float* cb = cout_ + (size_t)b * NPOSTS * HIDD;
    const int* dg = deg + b * NPOSTS;
    const int r0 = blockIdx.x * 16;
    const int tid = threadIdx.x;
    __shared__ float sx[16][S2VD];
    for (int i = tid; i < 16 * S2VD; i += 256)
        sx[i / S2VD][i % S2VD] = x[(size_t)(r0 + i / S2VD) * S2VD + (i % S2VD)];
    __syncthreads();
    float acc[16];
    #pragma unroll
    for (int r = 0; r < 16; ++r) acc[r] = 0.f;
    const float4* wr4 = reinterpret_cast<const float4*>(w + (size_t)tid * S2VD);
    for (int c4 = 0; c4 < 64; ++c4) {
        float4 w4 = wr4[c4];
        #pragma unroll
        for (int r = 0; r < 16; ++r) {
            const float4 v = *reinterpret_cast<const float4*>(&sx[r][c4 * 4]);
            acc[r] = fmaf(w4.x, v.x, acc[r]);
            acc[r] = fmaf(w4.y, v.y, acc[r]);
            acc[r] = fmaf(w4.z, v.z, acc[r]);
            acc[r] = fmaf(w4.w, v.w, acc[r]);
        }
    }
    float bv = bias[tid];
    #pragma unroll
    for (int r = 0; r < 16; ++r) {
        int n = r0 + r;
        float dinv = 1.f / (float)(dg[n] + 1);
        hb[(size_t)n * HIDD + tid] = acc[r];
        cb[(size_t)n * HIDD + tid] = bv + acc[r] * dinv;
    }
}

__global__ __launch_bounds__(256) void k_gemm2(
    const float* __restrict__ c1, const float* __restrict__ w2td, const float* __restrict__ w2bu,
    const float* __restrict__ btd, const float* __restrict__ bbu, const int* __restrict__ deg,
    const float* __restrict__ rootv, float* __restrict__ hout, float* __restrict__ cout_)
{
    const int b = blockIdx.y;
    const float* w = b ? w2bu : w2td;
    const float* bias = b ? bbu : btd;
    const float* xin = c1 + (size_t)b * NPOSTS * HIDD;
    float* hb = hout + (size_t)b * NPOSTS * HIDD;
    float* cb = cout_ + (size_t)b * NPOSTS * HIDD;
    const int* dg = deg + b * NPOSTS;
    const int r0 = blockIdx.x * 16;
    const int tid = threadIdx.x;
    __shared__ float sx[16][HIDD];
    for (int i = tid; i < 16 * HIDD; i += 256)
        sx[i / HIDD][i % HIDD] = fmaxf(xin[(size_t)(r0 + i / HIDD) * HIDD + (i % HIDD)], 0.f);
    __syncthreads();
    float acc[16];
    const float rv = rootv[b * HIDD + tid];
    #pragma unroll
    for (int r = 0; r < 16; ++r) acc[r] = rv;
    const float4* wr4 = reinterpret_cast<const float4*>(w + (size_t)tid * 512);
    for (int c4 = 0; c4 < 64; ++c4) {
        float4 w4 = wr4[c4];
        #pragma unroll
        for (int r = 0; r < 16; ++r) {
            const float4 v = *reinterpret_cast<const float4*>(&sx[r][c4 * 4]);
            acc[r] = fmaf(w4.x, v.x, acc[r]);
            acc[r] = fmaf(w4.y, v.y, acc[r]);
            acc[r] = fmaf(w4.z, v.z, acc[r]);
            acc[r] = fmaf(w4.w, v.w, acc[r]);
        }
    }
    float bv = bias[tid];
    #pragma unroll
    for (int r = 0; r < 16; ++r) {
        int n = r0 + r;
        float dinv = 1.f / (float)(dg[n] + 1);
        hb[(size_t)n * HIDD + tid] = acc[r];
        cb[(size_t)n * HIDD + tid] = bv + acc[r] * dinv;
    }
}

__global__ __launch_bounds__(256) void k_scat(
    const int* __restrict__ eiTD, const int* __restrict__ eiBU,
    const float* __restrict__ h, const int* __restrict__ deg, float* __restrict__ cacc)
{
    const int b = blockIdx.y, e = blockIdx.x, tid = threadIdx.x;
    const int* ei = b ? eiBU : eiTD;
    const int s = ei[e], d = ei[NEDGE + e];
    const int* dg = deg + b * NPOSTS;
    float norm = rsqrtf((float)(dg[s] + 1)) * rsqrtf((float)(dg[d] + 1));
    const float* hb = h + (size_t)b * NPOSTS * HIDD;
    float* cb = cacc + (size_t)b * NPOSTS * HIDD;
    atomicAdd(&cb[(size_t)d * HIDD + tid], norm * hb[(size_t)s * HIDD + tid]);
}

__global__ __launch_bounds__(256) void k_root(
    const float* __restrict__ s2v, const float* __restrict__ c1,
    const float* __restrict__ w2td, const float* __restrict__ w2bu,
    const int* __restrict__ rootPtr, float* __restrict__ rootv, float* __restrict__ c1root)
{
    const int b = blockIdx.y, tid = threadIdx.x;
    const float* w2 = b ? w2bu : w2td;
    const int root = rootPtr[0];
    __shared__ float sx[S2VD];
    sx[tid] = fmaxf(s2v[(size_t)root * S2VD + tid], 0.f);
    __syncthreads();
    const float* cb = c1 + (size_t)b * NPOSTS * HIDD;
    c1root[b * HIDD + tid] = cb[(size_t)root * HIDD + tid];
    const float* wr = w2 + (size_t)tid * 512 + 256;
    float acc = 0.f;
    #pragma unroll 4
    for (int c = 0; c < S2VD; ++c) acc = fmaf(wr[c], sx[c], acc);
    rootv[b * HIDD + tid] = acc;
}

__global__ __launch_bounds__(256) void k_reduce(
    const float* __restrict__ cacc, float* __restrict__ msum)
{
    const int b = blockIdx.y, tid = threadIdx.x;
    const int base = blockIdx.x * 32;
    const float* cb = cacc + (size_t)b * NPOSTS * HIDD;
    float local = 0.f;
    #pragma unroll 4
    for (int r = 0; r < 32; ++r) local += fmaxf(cb[(size_t)(base + r) * HIDD + tid], 0.f);
    atomicAdd(&msum[b * HIDD + tid], local);
}

__global__ __launch_bounds__(256) void k_final(
    const float* __restrict__ c1root, const float* __restrict__ msum,
    const float* __restrict__ fc_w, const float* __restrict__ fc_b, float* __restrict__ outp)
{
    const int tid = threadIdx.x;
    __shared__ float sf[1024];
    for (int k = tid; k < 1024; k += 256) {
        int seg = k >> 8, idx = k & 255;
        float v;
        if (seg == 0)      v = c1root[idx];
        else if (seg == 1) v = msum[idx] * (1.f / (float)NPOSTS);
        else if (seg == 2) v = c1root[256 + idx];
        else               v = msum[256 + idx] * (1.f / (float)NPOSTS);
        sf[k] = v;
    }
    __syncthreads();
    const int t = tid >> 6, lane = tid & 63;
    float part = 0.f;
    for (int k = lane; k < 1024; k += 64) part = fmaf(fc_w[t * 1024 + k], sf[k], part);
    #pragma unroll
    for (int off = 32; off > 0; off >>= 1) part += __shfl_down(part, off);
    if (lane == 0) outp[t] = part + fc_b[t];
}

extern "C" void kernel_launch(void* const* d_in, const int* in_sizes, int n_in,
                              void* d_out, int out_size, void* d_ws, size_t ws_size,
                              hipStream_t stream) {
    (void)in_sizes; (void)n_in; (void)out_size; (void)ws_size;

    const int*   nodeText   = (const int*)d_in[0];
    const int*   eiTD       = (const int*)d_in[1];
    const int*   eiBU       = (const int*)d_in[2];
    const int*   threadIdxP = (const int*)d_in[3];
    const float* embed_w    = (const float*)d_in[5];
    const float* in_proj_w  = (const float*)d_in[6];
    const float* in_proj_b  = (const float*)d_in[7];
    const float* out_proj_w = (const float*)d_in[8];
    const float* out_proj_b = (const float*)d_in[9];
    const float* s2v_w      = (const float*)d_in[10];
    const float* s2v_b      = (const float*)d_in[11];
    const float* td_w1      = (const float*)d_in[12];
    const float* td_b1      = (const float*)d_in[13];
    const float* td_w2      = (const float*)d_in[14];
    const float* td_b2      = (const float*)d_in[15];
    const float* bu_w1      = (const float*)d_in[16];
    const float* bu_b1      = (const float*)d_in[17];
    const float* bu_w2      = (const float*)d_in[18];
    const float* bu_b2      = (const float*)d_in[19];
    const float* fc_w       = (const float*)d_in[20];
    const float* fc_b       = (const float*)d_in[21];
    float* outp = (float*)d_out;

    // workspace layout
    char* w = (char*)d_ws;
    int*   deg    = (int*)w;                                          // 16384 B
    float* msum   = (float*)(w + 16384);                              // 2048 B
    float* rootv  = (float*)(w + 16384 + 2048);
    float* c1root = (float*)(w + 16384 + 4096);
    float* s2v    = (float*)(w + 24576);                              // 2 MB
    float* hbuf   = (float*)(w + 24576 + 2097152);                    // 4 MB
    float* cbuf   = (float*)(w + 24576 + 2097152 + 4194304);          // 4 MB
    float* Qbuf   = (float*)(w + 24576 + 2097152 + 4194304 + 4194304);             // 2.46 MB
    float* uebuf  = (float*)(w + 24576 + 2097152 + 4194304 + 4194304 + 2457600);   // 12.29 MB

    // folded-weight buffers alias hbuf/cbuf (consumed before k_gemm1/k_gemm2 write them)
    float* WfoldT = hbuf;                 // 1500*256 floats = 1.536 MB (transposed)
    float* WsWo   = cbuf;                 // 256*300
    float* bias3A = cbuf + 76800;         // 256
    float* bpart  = cbuf + 77056;         // 5*256

    hipMemsetAsync(d_ws, 0, 16384 + 2048, stream);

    // ---- independent prep ----
    k_deg<<<dim3((NEDGE + 255) / 256, 2), 256, 0, stream>>>(eiTD, eiBU, deg);
    k_wfoldA<<<16, 320, 0, stream>>>(s2v_w, out_proj_w, out_proj_b, s2v_b, WsWo, bias3A);
    k_wfold2<<<dim3(16, 5), 320, 0, stream>>>(WsWo, in_proj_w, in_proj_b, WfoldT, bpart);

    // ---- stage 1 ----
    k_q  <<<NPOSTS / 8, 320, 0, stream>>>(nodeText, embed_w, in_proj_w, in_proj_b, Qbuf);
    k_u  <<<dim3(NPOSTS / 16, 5), 320, 0, stream>>>(Qbuf, in_proj_w, uebuf);
    k_att<<<NPOSTS, 512, 0, stream>>>(nodeText, embed_w, uebuf);
    k_s2v<<<512, 256, 0, stream>>>(uebuf, WfoldT, bias3A, bpart, s2v);

    // ---- stage 2 ----
    k_gemm1<<<dim3(NPOSTS / 16, 2), 256, 0, stream>>>(s2v, td_w1, bu_w1, td_b1, bu_b1, deg,
                                                      hbuf, cbuf);
    k_scat<<<dim3(NEDGE, 2), 256, 0, stream>>>(eiTD, eiBU, hbuf, deg, cbuf);

    k_root<<<dim3(1, 2), 256, 0, stream>>>(s2v, cbuf, td_w2, bu_w2, threadIdxP, rootv, c1root);

    k_gemm2<<<dim3(NPOSTS / 16, 2), 256, 0, stream>>>(cbuf, td_w2, bu_w2, td_b2, bu_b2, deg,
                                                      rootv, hbuf, cbuf);
    k_scat<<<dim3(NEDGE, 2), 256, 0, stream>>>(eiTD, eiBU, hbuf, deg, cbuf);

    k_reduce<<<dim3(NPOSTS / 32, 2), 256, 0, stream>>>(cbuf, msum);

    k_final<<<1, 256, 0, stream>>>(c1root, msum, fc_w, fc_b, outp);
}